// Round 6
// baseline (1738.418 us; speedup 1.0000x reference)
//
#include <hip/hip_runtime.h>
#include <stdint.h>

// Net_11587821765063: sequential SNN scan, T=1000 steps.
// Output = spike_out (T,1,COUT) float32 only; w / traces are not returned.
//
// Math reductions (absmax 0 in rounds 1-5):
//  - potentiation p[t][i] = 2 if x[t][i] else (1 if (t==0 or x[t-1][i]) else 0)
//  - depression for row o at t = -x[t][i] iff (!spike[t][o] && spike[t-1][o]),
//    spike[-1] := true (cout init quirk).
//  - prohibit P[t] = 1 iff any spike at t-1 (grid-wide 1-bit OR); P[0]=0.
//
// Round 6 = round 5 (2-step prohibit speculation, absmax-0 validated) with
// the register blowup fixed: round 5's hypothesis arrays were demoted to LDS
// by PromoteAlloca (LDS_Block_Size 16896, 1.8e7 bank conflicts) and the
// 2-branch weight state spilled (VGPR_Count 64). This version scalarizes all
// per-step state, keeps the four weight-branch arrays flat with constant
// indices, and declares __launch_bounds__(512,2) (VGPR cap 256, need ~180).
// Poll retries back off with s_sleep to avoid MALL retry storms.
//
// Structure: 32 blocks x 512 threads (8 waves, 2 rows/wave, 13 cols/lane).
// Each block publishes 4 hypothesis bits per step u (any-own-row-spike under
// (P[u-1]=d, P[u]=c), bit k=(d<<1)|c). Line(u) is gathered at iteration u+2
// (two iterations of slack); wave0 resolves P[u-1] = A(u-2)[P[u-3]][P[u-2]]
// BEFORE the single per-step barrier. Outputs lag one step.

#define T_STEPS 1000
#define CIN     784
#define COUT    512
#define CPL     13            // columns per lane (64*13 = 832 >= 784)
#define NBLK    32
#define WPB     8             // waves per block
#define VTHR_F   12500.0f
#define PROHIB_F 11250.0f

#define SLOTS_WORDS (T_STEPS * NBLK)          // uint32 per (u, blk)
#define CODE_OFFSET 524288                    // 512 KiB, 16B-aligned

// ---- prep: zero slot words and pack per-(t,lane) 16-byte code slot:
// byte j (j<13) encodes col = lane*13+j: bit0 = x[t][col], bits[2:1] = p.
__global__ __launch_bounds__(256) void prep_kernel(const int* __restrict__ x,
                                                   uint8_t* __restrict__ code,
                                                   uint32_t* __restrict__ slots) {
    int gid = blockIdx.x * blockDim.x + threadIdx.x;   // one per (t, lane)
    if (gid >= T_STEPS * 64) return;
    if (gid < SLOTS_WORDS) slots[gid] = 0u;            // 32000 dwords
    int t = gid >> 6;
    int lane = gid & 63;
    uint32_t wds[4] = {0u, 0u, 0u, 0u};
    #pragma unroll
    for (int j = 0; j < CPL; ++j) {
        int col = lane * CPL + j;
        uint32_t b = 0u;
        if (col < CIN) {
            int xc = x[t * CIN + col];
            int xp = (t > 0) ? x[(t - 1) * CIN + col] : 0;
            int p = xc ? 2 : ((t == 0) ? 1 : (xp ? 1 : 0));
            b = (uint32_t)((xc & 1) | (p << 1));
        }
        wds[j >> 2] |= b << ((j & 3) * 8);
    }
    ((uint4*)code)[gid] = make_uint4(wds[0], wds[1], wds[2], wds[3]);
}

__global__ __launch_bounds__(512, 2) void snn_kernel(const float* __restrict__ weight,
                                                     const uint8_t* __restrict__ code,
                                                     uint32_t* __restrict__ slots,
                                                     float* __restrict__ out) {
    __shared__ int sh_h[2][WPB];    // double-buffered per-wave hypothesis bits
    __shared__ int sh_b[2];         // double-buffered resolved branch bit

    const int tid  = threadIdx.x;
    const int wave = tid >> 6;
    const int lane = tid & 63;
    const int blk  = blockIdx.x;
    const int row0 = blk * (WPB * 2) + wave * 2;

    // two branch weight states x two rows — flat arrays, constant indices only
    float wA0[CPL], wA1[CPL], wB0[CPL], wB1[CPL];
    #pragma unroll
    for (int j = 0; j < CPL; ++j) {
        int col = lane * CPL + j;
        float v0 = (col < CIN) ? weight[(row0 + 0) * CIN + col] : 0.0f;
        float v1 = (col < CIN) ? weight[(row0 + 1) * CIN + col] : 0.0f;
        wA0[j] = v0; wB0[j] = v0;
        wA1[j] = v1; wB1[j] = v1;
    }

    const uint4* code4 = (const uint4*)code;
    uint4 cw  = code4[lane];               // codes for u=0
    uint4 cwn = code4[64 + lane];          // codes for u=1 (prefetch)

    float memA0 = 0.0f, memA1 = 0.0f, memB0 = 0.0f, memB1 = 0.0f;
    bool  psA0 = true, psA1 = true, psB0 = true, psB1 = true;  // spike(-1)=true
    int p2 = 0, p3 = 0;                    // wave0: actual P[u-2], P[u-3]

    float xf[CPL], pf[CPL];

    for (int u = 0; u < T_STEPS; ++u) {
        // ---- wave0: early prefetch of line(u-2) (use is ~1000 cyc later) ----
        const uint32_t* gl = slots + (size_t)(u >= 2 ? u - 2 : 0) * NBLK;
        uint32_t gv = 0xB0u;
        if (wave == 0 && u >= 2 && lane < NBLK)
            gv = __hip_atomic_load(&gl[lane], __ATOMIC_RELAXED,
                                   __HIP_MEMORY_SCOPE_AGENT);

        // ---- decode codes for step u ----
        uint32_t cwd[4] = {cw.x, cw.y, cw.z, cw.w};
        #pragma unroll
        for (int j = 0; j < CPL; ++j) {
            uint32_t c = (cwd[j >> 2] >> ((j & 3) * 8)) & 0xFFu;
            xf[j] = (float)(c & 1u);
            pf[j] = (float)(c >> 1);
        }

        // ---- four dots (2 rows x 2 weight branches), exact order as r5 ----
        float dA0 = 0.0f, dA1 = 0.0f, dB0 = 0.0f, dB1 = 0.0f;
        #pragma unroll
        for (int j = 0; j < CPL; ++j) {
            dA0 += xf[j] * wA0[j];         // exact: x in {0,1}
            dA1 += xf[j] * wA1[j];
            dB0 += xf[j] * wB0[j];
            dB1 += xf[j] * wB1[j];
        }

        // ---- folded reduction of 4 sums (bit-identical tree to r5) ----
        bool half = (lane & 32) != 0;
        float kx = half ? dB0 : dA0;
        float ky = half ? dB1 : dA1;
        float sx = half ? dA0 : dB0;
        float sy = half ? dA1 : dB1;
        kx += __shfl_xor(sx, 32, 64);
        ky += __shfl_xor(sy, 32, 64);
        bool subq = (lane & 16) != 0;
        float kk = subq ? ky : kx;
        float ss = subq ? kx : ky;
        kk += __shfl_xor(ss, 16, 64);
        kk += __shfl_xor(kk, 8, 64);
        kk += __shfl_xor(kk, 4, 64);
        kk += __shfl_xor(kk, 2, 64);
        kk += __shfl_xor(kk, 1, 64);
        float b1 = __shfl_xor(kk, 16, 64);
        float b2 = __shfl_xor(kk, 32, 64);
        float b3 = __shfl_xor(b1, 32, 64);
        int q = lane >> 4;
        float dotA0 = (q == 0) ? kk : (q == 1) ? b1 : (q == 2) ? b2 : b3;
        float dotA1 = (q == 0) ? b1 : (q == 1) ? kk : (q == 2) ? b3 : b2;
        float dotB0 = (q == 0) ? b2 : (q == 1) ? b3 : (q == 2) ? kk : b1;
        float dotB1 = (q == 0) ? b3 : (q == 1) ? b2 : (q == 2) ? b1 : kk;

        // ---- 4 hypotheses (d = P[u-1] branch, c = P[u] branch), scalars ----
        float sa0 = memA0 + dotA0;         // reference op order
        float sa1 = memA1 + dotA1;
        float sb0 = memB0 + dotB0;
        float sb1 = memB1 + dotB1;
        float m00_0 = fmaxf(sa0, 0.0f),            m00_1 = fmaxf(sa1, 0.0f);
        float m01_0 = fmaxf(sa0 - PROHIB_F, 0.0f), m01_1 = fmaxf(sa1 - PROHIB_F, 0.0f);
        float m10_0 = fmaxf(sb0, 0.0f),            m10_1 = fmaxf(sb1, 0.0f);
        float m11_0 = fmaxf(sb0 - PROHIB_F, 0.0f), m11_1 = fmaxf(sb1 - PROHIB_F, 0.0f);
        bool s00_0 = m00_0 >= VTHR_F, s00_1 = m00_1 >= VTHR_F;
        bool s01_0 = m01_0 >= VTHR_F, s01_1 = m01_1 >= VTHR_F;
        bool s10_0 = m10_0 >= VTHR_F, s10_1 = m10_1 >= VTHR_F;
        bool s11_0 = m11_0 >= VTHR_F, s11_1 = m11_1 >= VTHR_F;
        int hb = ((s00_0 || s00_1) ? 1 : 0) | ((s01_0 || s01_1) ? 2 : 0) |
                 ((s10_0 || s10_1) ? 4 : 0) | ((s11_0 || s11_1) ? 8 : 0);
        if (lane == 0) sh_h[u & 1][wave] = hb;

        // ---- wave0: resolve P[u-1] from line(u-2) (before the barrier) ----
        if (wave == 0) {
            int bstar = 0;
            if (u >= 2) {
                bool ok = ((gv & 0xF0u) == 0xB0u);   // lanes>=NBLK pass (gv=0xB0)
                while (!__all(ok)) {
                    __builtin_amdgcn_s_sleep(1);     // backoff: don't flood MALL
                    if (lane < NBLK)
                        gv = __hip_atomic_load(&gl[lane], __ATOMIC_RELAXED,
                                               __HIP_MEMORY_SCOPE_AGENT);
                    ok = ((gv & 0xF0u) == 0xB0u);
                }
                uint32_t vm = (lane < NBLK) ? gv : 0u;
                int k = (p3 << 1) | p2;              // wave-uniform
                bstar = __any((int)((vm >> k) & 1u));
            }
            p3 = p2; p2 = bstar;
            if (lane == 0) sh_b[u & 1] = bstar;
        }
        __syncthreads();                             // single barrier per step

        // ---- wave0 lane0: publish this step's 4 hypothesis bits ----
        if (wave == 0 && lane == 0) {
            int hh = sh_h[u & 1][0] | sh_h[u & 1][1] | sh_h[u & 1][2] |
                     sh_h[u & 1][3] | sh_h[u & 1][4] | sh_h[u & 1][5] |
                     sh_h[u & 1][6] | sh_h[u & 1][7];
            __hip_atomic_store(&slots[(size_t)u * NBLK + blk],
                               0xB0u | (uint32_t)hh,
                               __ATOMIC_RELAXED, __HIP_MEMORY_SCOPE_AGENT);
        }
        const int bst = sh_b[u & 1];                 // resolved P[u-1]

        // ---- collapse branch d=bst; emit out(u-1); rebranch over c=P[u] ----
        bool sprv0 = bst ? psB0 : psA0;              // actual spike(u-1)
        bool sprv1 = bst ? psB1 : psA1;
        bool sc0_0 = bst ? s10_0 : s00_0;            // c=0 spikes
        bool sc0_1 = bst ? s10_1 : s00_1;
        bool sc1_0 = bst ? s11_0 : s01_0;            // c=1 spikes
        bool sc1_1 = bst ? s11_1 : s01_1;
        float mc0_0 = bst ? m10_0 : m00_0;
        float mc0_1 = bst ? m10_1 : m00_1;
        float mc1_0 = bst ? m11_0 : m01_0;
        float mc1_1 = bst ? m11_1 : m01_1;

        if (u >= 1 && lane == 0)
            *(float2*)(out + (size_t)(u - 1) * COUT + row0) =
                make_float2(sprv0 ? 1.0f : 0.0f, sprv1 ? 1.0f : 0.0f);

        memA0 = sc0_0 ? 0.0f : mc0_0;
        memA1 = sc0_1 ? 0.0f : mc0_1;
        memB0 = sc1_0 ? 0.0f : mc1_0;
        memB1 = sc1_1 ? 0.0f : mc1_1;

        auto upd_row = [&](float (&wAr)[CPL], float (&wBr)[CPL],
                           bool sc0, bool sc1, bool sprv) {
            if (bst) {
                #pragma unroll
                for (int j = 0; j < CPL; ++j) wAr[j] = wBr[j];
            }
            if (sc1) {                     // branch c=1 into wB (from collapsed wA)
                #pragma unroll
                for (int j = 0; j < CPL; ++j)
                    wBr[j] = fminf(wAr[j] + pf[j], 127.0f);
            } else if (sprv) {
                #pragma unroll
                for (int j = 0; j < CPL; ++j)
                    wBr[j] = fmaxf(wAr[j] - xf[j], 0.0f);
            } else {
                #pragma unroll
                for (int j = 0; j < CPL; ++j) wBr[j] = wAr[j];
            }
            if (sc0) {                     // branch c=0 in place into wA
                #pragma unroll
                for (int j = 0; j < CPL; ++j)
                    wAr[j] = fminf(wAr[j] + pf[j], 127.0f);
            } else if (sprv) {
                #pragma unroll
                for (int j = 0; j < CPL; ++j)
                    wAr[j] = fmaxf(wAr[j] - xf[j], 0.0f);
            }
        };
        upd_row(wA0, wB0, sc0_0, sc1_0, sprv0);
        upd_row(wA1, wB1, sc0_1, sc1_1, sprv1);
        psA0 = sc0_0; psA1 = sc0_1;
        psB0 = sc1_0; psB1 = sc1_1;

        uint4 cw2 = (u + 2 < T_STEPS) ? code4[(size_t)(u + 2) * 64 + lane]
                                      : make_uint4(0u, 0u, 0u, 0u);
        cw = cwn; cwn = cw2;
    }

    // ---- epilogue: resolve P[T-1] and write out(T-1) ----
    {
        if (wave == 0) {
            const uint32_t* gl2 = slots + (size_t)(T_STEPS - 2) * NBLK;
            uint32_t gv2 = 0xB0u;
            bool ok;
            do {
                if (lane < NBLK)
                    gv2 = __hip_atomic_load(&gl2[lane], __ATOMIC_RELAXED,
                                            __HIP_MEMORY_SCOPE_AGENT);
                ok = ((gv2 & 0xF0u) == 0xB0u);
            } while (!__all(ok));
            uint32_t vm = (lane < NBLK) ? gv2 : 0u;
            int k = (p3 << 1) | p2;
            int cst = __any((int)((vm >> k) & 1u));
            if (lane == 0) sh_b[T_STEPS & 1] = cst;
        }
        __syncthreads();
        int cst = sh_b[T_STEPS & 1];
        if (lane == 0) {
            bool s0r = cst ? psB0 : psA0;
            bool s1r = cst ? psB1 : psA1;
            *(float2*)(out + (size_t)(T_STEPS - 1) * COUT + row0) =
                make_float2(s0r ? 1.0f : 0.0f, s1r ? 1.0f : 0.0f);
        }
    }
}

extern "C" void kernel_launch(void* const* d_in, const int* in_sizes, int n_in,
                              void* d_out, int out_size, void* d_ws, size_t ws_size,
                              hipStream_t stream) {
    const int*   x      = (const int*)d_in[0];     // (T,1,CIN) int32
    const float* weight = (const float*)d_in[1];   // (COUT,CIN) f32
    float* out = (float*)d_out;                    // (T,1,COUT) f32

    uint32_t* slots = (uint32_t*)d_ws;
    uint8_t*  code  = (uint8_t*)d_ws + CODE_OFFSET;

    int prep_threads = T_STEPS * 64;
    prep_kernel<<<(prep_threads + 255) / 256, 256, 0, stream>>>(x, code, slots);
    snn_kernel<<<NBLK, WPB * 64, 0, stream>>>(weight, code, slots, out);
}

// Round 7
// 1474.649 us; speedup vs baseline: 1.1789x; 1.1789x over previous
//
#include <hip/hip_runtime.h>
#include <stdint.h>

// Net_11587821765063: sequential SNN scan, T=1000 steps.
// Output = spike_out (T,1,COUT) float32 only; w / traces are not returned.
//
// Math reductions (absmax 0 in rounds 1-6):
//  - potentiation p[t][i] = 2 if x[t][i] else (1 if (t==0 or x[t-1][i]) else 0)
//  - depression for row o at t = -x[t][i] iff (!spike[t][o] && spike[t-1][o]),
//    spike[-1] := true (cout init quirk).
//  - prohibit P[t] = 1 iff any spike at t-1 (grid-wide 1-bit OR); P[0]=0.
//
// Round 7: issue-bound fix. r6 was ~67% per-active-SIMD VALU busy with ~680
// predicated instr/wave/step (if-converted weight updates dominate). Changes:
//  - 128 blocks x 4 waves, 1 row/wave -> 1 wave/SIMD (full issue rate),
//    4x less per-wave row work.
//  - wave-uniform s_cbranch weight updates (readfirstlane'd conditions):
//    only the taken path issues; pf decoded lazily inside the branch.
//  - branch-equality (eq) fast path: when both prohibit hypotheses give the
//    same spike and membrane (common: rows spike nearly every step), the two
//    weight branches are identical -> skip B-dot and B-update.
//  - 2-step prohibit speculation as r5/r6: block publishes 4 hypothesis bits
//    (any-own-row-spike under (P[u-1]=d, P[u]=c), bit k=(d<<1)|c); line(u)
//    gathered at u+2 (one uint64 load/lane covers all 128 block words);
//    wave0 resolves P[u-1] = A(u-2)[P[u-3]][P[u-2]] before the single
//    per-step barrier. Outputs lag one step.

#define T_STEPS 1000
#define CIN     784
#define COUT    512
#define CPL     13            // columns per lane (64*13 = 832 >= 784)
#define NBLK    128
#define WPB     4             // waves per block, 1 row per wave
#define VTHR_F   12500.0f
#define PROHIB_F 11250.0f

#define SLOTS_WORDS (T_STEPS * NBLK)          // uint32 per (u, blk) = 128000
#define CODE_OFFSET 524288                    // 512 KiB >= 512000 B of slots
// code: T*64 uint4 = 1,024,000 B

// ---- prep: zero slot words and pack per-(t,lane) 16-byte code slot:
// byte j (j<13) encodes col = lane*13+j: bit0 = x[t][col], bits[2:1] = p.
__global__ __launch_bounds__(256) void prep_kernel(const int* __restrict__ x,
                                                   uint8_t* __restrict__ code,
                                                   uint2* __restrict__ slots2) {
    int gid = blockIdx.x * blockDim.x + threadIdx.x;   // one per (t, lane)
    if (gid >= T_STEPS * 64) return;
    slots2[gid] = make_uint2(0u, 0u);                  // 64000 x 8B = 512000 B
    int t = gid >> 6;
    int lane = gid & 63;
    uint32_t wds[4] = {0u, 0u, 0u, 0u};
    #pragma unroll
    for (int j = 0; j < CPL; ++j) {
        int col = lane * CPL + j;
        uint32_t b = 0u;
        if (col < CIN) {
            int xc = x[t * CIN + col];
            int xp = (t > 0) ? x[(t - 1) * CIN + col] : 0;
            int p = xc ? 2 : ((t == 0) ? 1 : (xp ? 1 : 0));
            b = (uint32_t)((xc & 1) | (p << 1));
        }
        wds[j >> 2] |= b << ((j & 3) * 8);
    }
    ((uint4*)code)[gid] = make_uint4(wds[0], wds[1], wds[2], wds[3]);
}

__device__ __forceinline__ int rfl(bool b) {      // force SGPR / s_cbranch
    return __builtin_amdgcn_readfirstlane(b ? 1 : 0);
}

__global__ __launch_bounds__(256, 1) void snn_kernel(const float* __restrict__ weight,
                                                     const uint8_t* __restrict__ code,
                                                     uint32_t* __restrict__ slots,
                                                     float* __restrict__ out) {
    __shared__ int sh_h[2][WPB];    // double-buffered per-wave hypothesis bits
    __shared__ int sh_b[2];         // double-buffered resolved branch bit

    const int tid  = threadIdx.x;
    const int wave = tid >> 6;
    const int lane = tid & 63;
    const int blk  = blockIdx.x;
    const int row  = blk * WPB + wave;

    float wA[CPL], wB[CPL];
    #pragma unroll
    for (int j = 0; j < CPL; ++j) {
        int col = lane * CPL + j;
        float v = (col < CIN) ? weight[row * CIN + col] : 0.0f;
        wA[j] = v; wB[j] = v;
    }

    const uint4* code4 = (const uint4*)code;
    uint4 cw  = code4[lane];               // codes for u=0
    uint4 cwn = code4[64 + lane];          // codes for u=1 (prefetch)

    float memA = 0.0f, memB = 0.0f;
    bool  psA = true, psB = true;          // spike(-1)=true quirk
    bool  eq  = true;                      // wB == wA (and memB==memA, psB==psA)
    int p2 = 0, p3 = 0;                    // wave0: actual P[u-2], P[u-3]

    for (int u = 0; u < T_STEPS; ++u) {
        // ---- wave0: early prefetch of line(u-2): 64 lanes x 8B = 128 dwords
        const unsigned long long* gl =
            (const unsigned long long*)(slots + (size_t)(u >= 2 ? u - 2 : 0) * NBLK);
        unsigned long long gv = 0xB0000000B0ull;       // sentinel-passing dummy
        if (wave == 0 && u >= 2)
            gv = __hip_atomic_load(&gl[lane], __ATOMIC_RELAXED,
                                   __HIP_MEMORY_SCOPE_AGENT);

        // ---- decode x bits for step u; dot(s) ----
        uint32_t cwd[4] = {cw.x, cw.y, cw.z, cw.w};
        float xf[CPL];
        #pragma unroll
        for (int j = 0; j < CPL; ++j)
            xf[j] = (float)((cwd[j >> 2] >> ((j & 3) * 8)) & 1u);
        float dA = 0.0f;
        #pragma unroll
        for (int j = 0; j < CPL; ++j) dA += xf[j] * wA[j];   // exact: x in {0,1}
        float dB;
        if (rfl(eq)) {
            dB = dA;                       // wB == wA -> bit-identical
        } else {
            dB = 0.0f;
            #pragma unroll
            for (int j = 0; j < CPL; ++j) dB += xf[j] * wB[j];
        }

        // ---- folded 2-value reduction (same xor tree shape as r1-r6) ----
        bool hi = (lane & 32) != 0;
        float k0 = hi ? dB : dA;
        float s0 = hi ? dA : dB;
        k0 += __shfl_xor(s0, 32, 64);
        k0 += __shfl_xor(k0, 16, 64);
        k0 += __shfl_xor(k0, 8, 64);
        k0 += __shfl_xor(k0, 4, 64);
        k0 += __shfl_xor(k0, 2, 64);
        k0 += __shfl_xor(k0, 1, 64);
        float ot = __shfl_xor(k0, 32, 64);
        float dotA = hi ? ot : k0;
        float dotB = hi ? k0 : ot;

        // ---- 4 hypotheses (d = P[u-1] branch, c = P[u] branch) ----
        float sa = memA + dotA;            // reference op order
        float sb = memB + dotB;
        float m00 = fmaxf(sa, 0.0f),            m01 = fmaxf(sa - PROHIB_F, 0.0f);
        float m10 = fmaxf(sb, 0.0f),            m11 = fmaxf(sb - PROHIB_F, 0.0f);
        bool s00 = m00 >= VTHR_F, s01 = m01 >= VTHR_F;
        bool s10 = m10 >= VTHR_F, s11 = m11 >= VTHR_F;
        int hb = (s00 ? 1 : 0) | (s01 ? 2 : 0) | (s10 ? 4 : 0) | (s11 ? 8 : 0);
        if (lane == 0) sh_h[u & 1][wave] = hb;

        // ---- wave0: resolve P[u-1] from line(u-2) (before the barrier) ----
        if (wave == 0) {
            int bstar = 0;
            if (u >= 2) {
                bool ok = ((gv & 0xF0000000F0ull) == 0xB0000000B0ull);
                while (!__all(ok)) {
                    __builtin_amdgcn_s_sleep(1);       // backoff
                    gv = __hip_atomic_load(&gl[lane], __ATOMIC_RELAXED,
                                           __HIP_MEMORY_SCOPE_AGENT);
                    ok = ((gv & 0xF0000000F0ull) == 0xB0000000B0ull);
                }
                uint32_t comb = (uint32_t)gv | (uint32_t)(gv >> 32);
                int kk = (p3 << 1) | p2;               // wave-uniform
                bstar = __any((int)((comb >> kk) & 1u));
            }
            p3 = p2; p2 = bstar;
            if (lane == 0) sh_b[u & 1] = bstar;
        }
        __syncthreads();                               // single barrier per step

        // ---- wave0 lane0: publish this step's 4 hypothesis bits ----
        if (wave == 0 && lane == 0) {
            int hh = sh_h[u & 1][0] | sh_h[u & 1][1] |
                     sh_h[u & 1][2] | sh_h[u & 1][3];
            __hip_atomic_store(&slots[(size_t)u * NBLK + blk],
                               0xB0u | (uint32_t)hh,
                               __ATOMIC_RELAXED, __HIP_MEMORY_SCOPE_AGENT);
        }
        const int bst = sh_b[u & 1];                   // resolved P[u-1]

        // ---- collapse branch d=bst; emit out(u-1); rebranch over c=P[u] ----
        bool sprv = bst ? psB : psA;                   // actual spike(u-1)
        bool sc0  = bst ? s10 : s00;                   // spike under c=0
        bool sc1  = bst ? s11 : s01;                   // spike under c=1
        float mc0 = bst ? m10 : m00;
        float mc1 = bst ? m11 : m01;

        if (u >= 1 && lane == 0)
            out[(size_t)(u - 1) * COUT + row] = sprv ? 1.0f : 0.0f;

        memA = sc0 ? 0.0f : mc0;
        memB = sc1 ? 0.0f : mc1;
        bool eqNext = (sc0 == sc1) && (memA == memB);

        // collapse weights to the resolved d-branch (only if they differ)
        if (rfl(bst && !eq)) {
            #pragma unroll
            for (int j = 0; j < CPL; ++j) wA[j] = wB[j];
        }
        // wave-uniform branchy updates: only the taken path issues
        if (rfl(eqNext)) {
            if (rfl(sc0)) {                // potentiate (common path)
                #pragma unroll
                for (int j = 0; j < CPL; ++j) {
                    float pfj = (float)((cwd[j >> 2] >> ((j & 3) * 8 + 1)) & 3u);
                    wA[j] = fminf(wA[j] + pfj, 127.0f);
                }
            } else if (rfl(sprv)) {        // depress
                #pragma unroll
                for (int j = 0; j < CPL; ++j)
                    wA[j] = fmaxf(wA[j] - xf[j], 0.0f);
            }
            // wB stale; eq flag covers it
        } else {
            // divergent: build wB from pre-update wA base (c=1 path)
            if (rfl(sc1)) {
                #pragma unroll
                for (int j = 0; j < CPL; ++j) {
                    float pfj = (float)((cwd[j >> 2] >> ((j & 3) * 8 + 1)) & 3u);
                    wB[j] = fminf(wA[j] + pfj, 127.0f);
                }
            } else if (rfl(sprv)) {
                #pragma unroll
                for (int j = 0; j < CPL; ++j)
                    wB[j] = fmaxf(wA[j] - xf[j], 0.0f);
            } else {
                #pragma unroll
                for (int j = 0; j < CPL; ++j) wB[j] = wA[j];
            }
            if (rfl(sc0)) {                // c=0 path in place
                #pragma unroll
                for (int j = 0; j < CPL; ++j) {
                    float pfj = (float)((cwd[j >> 2] >> ((j & 3) * 8 + 1)) & 3u);
                    wA[j] = fminf(wA[j] + pfj, 127.0f);
                }
            } else if (rfl(sprv)) {
                #pragma unroll
                for (int j = 0; j < CPL; ++j)
                    wA[j] = fmaxf(wA[j] - xf[j], 0.0f);
            }
        }
        psA = sc0; psB = sc1; eq = eqNext;

        uint4 cw2 = (u + 2 < T_STEPS) ? code4[(size_t)(u + 2) * 64 + lane]
                                      : make_uint4(0u, 0u, 0u, 0u);
        cw = cwn; cwn = cw2;
    }

    // ---- epilogue: resolve P[T-1] and write out(T-1) ----
    {
        if (wave == 0) {
            const unsigned long long* gl2 =
                (const unsigned long long*)(slots + (size_t)(T_STEPS - 2) * NBLK);
            unsigned long long gv2;
            bool ok;
            do {
                gv2 = __hip_atomic_load(&gl2[lane], __ATOMIC_RELAXED,
                                        __HIP_MEMORY_SCOPE_AGENT);
                ok = ((gv2 & 0xF0000000F0ull) == 0xB0000000B0ull);
            } while (!__all(ok));
            uint32_t comb = (uint32_t)gv2 | (uint32_t)(gv2 >> 32);
            int kk = (p3 << 1) | p2;
            int cst = __any((int)((comb >> kk) & 1u));
            if (lane == 0) sh_b[T_STEPS & 1] = cst;
        }
        __syncthreads();
        int cst = sh_b[T_STEPS & 1];
        if (lane == 0) {
            bool sr = cst ? psB : psA;
            out[(size_t)(T_STEPS - 1) * COUT + row] = sr ? 1.0f : 0.0f;
        }
    }
}

extern "C" void kernel_launch(void* const* d_in, const int* in_sizes, int n_in,
                              void* d_out, int out_size, void* d_ws, size_t ws_size,
                              hipStream_t stream) {
    const int*   x      = (const int*)d_in[0];     // (T,1,CIN) int32
    const float* weight = (const float*)d_in[1];   // (COUT,CIN) f32
    float* out = (float*)d_out;                    // (T,1,COUT) f32

    uint32_t* slots = (uint32_t*)d_ws;
    uint8_t*  code  = (uint8_t*)d_ws + CODE_OFFSET;

    int prep_threads = T_STEPS * 64;
    prep_kernel<<<(prep_threads + 255) / 256, 256, 0, stream>>>(x, code,
                                                                (uint2*)slots);
    snn_kernel<<<NBLK, WPB * 64, 0, stream>>>(weight, code, slots, out);
}